// Round 4
// baseline (192.278 us; speedup 1.0000x reference)
//
#include <hip/hip_runtime.h>
#include <math.h>

#define BB 16
#define CC 3
#define HH 512
#define WW 512
#define HW (HH*WW)            // 262144
#define TOTAL ((double)(BB*CC*HW))  // 12582912

#define TSTR 40               // LDS tile row stride in floats (div by 4 -> 16B-aligned interior)

// ws layout (bytes):
//   [0)     : double ps[4096]   per-block interior sum of r_sr        32768 B
//   [32768) : double pss[4096]  per-block interior sum of r_sr^2      32768 B
//   [65536) : double pl[4096]   per-block loss partial (no patch w)   32768 B

// One block = one 32x32 output tile (grid 16x16x16 = 4096 blocks).
// LDS tile holds encoded r_sr for the 38x38 halo region:
//   value = sum_c |gt-out|, sign bit set iff r_sr < r_ema (interior only; halo never a center).
__global__ __launch_bounds__(256, 8) void k_main(
    const float* __restrict__ outp, const float* __restrict__ emap,
    const float* __restrict__ gtp,
    double* __restrict__ ps, double* __restrict__ pss, double* __restrict__ pl)
{
    __shared__ float tile[38 * TSTR];
    __shared__ double red[12];

    const int t  = threadIdx.x;
    const int bx = blockIdx.x, by = blockIdx.y, b = blockIdx.z;
    const int x0 = bx * 32 - 3, y0 = by * 32 - 3;

    const size_t ib = (size_t)b * (CC * HW);
    const float4* o4 = (const float4*)(outp + ib);
    const float4* e4 = (const float4*)(emap + ib);
    const float4* g4 = (const float4*)(gtp + ib);

    double s_loc = 0.0, ss_loc = 0.0;

    // ---- Phase A: interior 32x32, one float4 per thread; ema read here only ----
    {
        int row = t >> 3;                 // 0..31
        int fc  = t & 7;                  // 0..7 (float4 col within tile)
        int idx = (by * 32 + row) * (WW / 4) + (bx * 8 + fc);
        float4 rs = {0.f, 0.f, 0.f, 0.f};
        float4 re = {0.f, 0.f, 0.f, 0.f};
#pragma unroll
        for (int c = 0; c < CC; ++c) {
            float4 g = g4[c * (HW / 4) + idx];
            float4 o = o4[c * (HW / 4) + idx];
            float4 e = e4[c * (HW / 4) + idx];
            rs.x += fabsf(g.x - o.x); rs.y += fabsf(g.y - o.y);
            rs.z += fabsf(g.z - o.z); rs.w += fabsf(g.w - o.w);
            re.x += fabsf(g.x - e.x); re.y += fabsf(g.y - e.y);
            re.z += fabsf(g.z - e.z); re.w += fabsf(g.w - e.w);
        }
        float4 enc;
        enc.x = (rs.x < re.x) ? -rs.x : rs.x;
        enc.y = (rs.y < re.y) ? -rs.y : rs.y;
        enc.z = (rs.z < re.z) ? -rs.z : rs.z;
        enc.w = (rs.w < re.w) ? -rs.w : rs.w;
        *(float4*)&tile[(row + 3) * TSTR + 4 + fc * 4] = enc;

        s_loc  += (double)rs.x + (double)rs.y + (double)rs.z + (double)rs.w;
        ss_loc += (double)rs.x * rs.x + (double)rs.y * rs.y +
                  (double)rs.z * rs.z + (double)rs.w * rs.w;
    }

    // ---- Phase B: halo ring (420 positions), scalar, reflect-mapped ----
    for (int i = t; i < 420; i += 256) {
        int ly, lx;
        if (i < 114)      { ly = i / 38;                 lx = i % 38; }
        else if (i < 228) { int j = i - 114; ly = 35 + j / 38;  lx = j % 38; }
        else if (i < 324) { int j = i - 228; ly = 3 + (j & 31); lx = j >> 5; }
        else              { int j = i - 324; ly = 3 + (j & 31); lx = 35 + (j >> 5); }
        int gy = y0 + ly; gy = gy < 0 ? -gy : (gy >= HH ? 2 * HH - 2 - gy : gy);
        int gx = x0 + lx; gx = gx < 0 ? -gx : (gx >= WW ? 2 * WW - 2 - gx : gx);
        size_t idx = ib + (size_t)(gy * WW + gx);
        float r = 0.f;
#pragma unroll
        for (int c = 0; c < CC; ++c) {
            float g = gtp[idx + c * HW];
            float o = outp[idx + c * HW];
            r += fabsf(g - o);
        }
        tile[ly * TSTR + 1 + lx] = r;     // r >= +0, sign bit clear
    }
    __syncthreads();

    // ---- Phase C: separable 7x7 variance, row sums in a 7-deep register ring ----
    const int x  = t & 31;                // output col
    const int w  = t >> 5;                // strip: 4 output rows (8 strips)
    const int r0 = w * 4;

    float rS[7], rSS[7];
    float winS = 0.f, winSS = 0.f;
#pragma unroll
    for (int j = 0; j < 7; ++j) {
        float S = 0.f, SS = 0.f;
#pragma unroll
        for (int dx = 0; dx < 7; ++dx) {
            float v = tile[(r0 + j) * TSTR + x + 1 + dx];
            S += fabsf(v);
            SS = fmaf(v, v, SS);
        }
        rS[j] = S; rSS[j] = SS;
        winS += S; winSS += SS;
    }
    double acc = 0.0;
#pragma unroll
    for (int k = 0; k < 4; ++k) {
        if (k) {
            const int slot = k - 1;                // static (unrolled)
            float S = 0.f, SS = 0.f;
#pragma unroll
            for (int dx = 0; dx < 7; ++dx) {
                float v = tile[(r0 + k + 6) * TSTR + x + 1 + dx];
                S += fabsf(v);
                SS = fmaf(v, v, SS);
            }
            winS  += S  - rS[slot];
            winSS += SS - rSS[slot];
            rS[slot] = S; rSS[slot] = SS;
        }
        float cen = tile[(r0 + k + 3) * TSTR + x + 4];
        float rr  = fabsf(cen);
        float pvar = (winSS - winS * winS * (1.0f / 49.0f)) * (1.0f / 48.0f);
        float contrib = (__float_as_uint(cen) >> 31) ? 0.0f : fabsf(pvar) * rr;
        acc += (double)contrib;
    }

    // ---- block reduction -> per-block slots (no atomics, no init needed) ----
    for (int off = 32; off; off >>= 1) {
        s_loc  += __shfl_down(s_loc, off);
        ss_loc += __shfl_down(ss_loc, off);
        acc    += __shfl_down(acc, off);
    }
    const int wid = t >> 6;
    if ((t & 63) == 0) { red[wid] = s_loc; red[4 + wid] = ss_loc; red[8 + wid] = acc; }
    __syncthreads();
    if (t == 0) {
        int bid = b * 256 + by * 16 + bx;
        ps[bid]  = red[0] + red[1] + red[2] + red[3];
        pss[bid] = red[4] + red[5] + red[6] + red[7];
        pl[bid]  = red[8] + red[9] + red[10] + red[11];
    }
}

// ---- final: per-image variance -> patch weight, weighted total, mean ----
__global__ __launch_bounds__(256) void k_final(
    const double* __restrict__ ps, const double* __restrict__ pss,
    const double* __restrict__ pl, float* __restrict__ out)
{
    const int t = threadIdx.x, lane = t & 63, w = t >> 6;
    __shared__ double sh_s[4], sh_ss[4], sh_l[4];
    __shared__ double tot_sh;
    if (t == 0) tot_sh = 0.0;
    __syncthreads();

    for (int b = 0; b < BB; ++b) {
        double s  = ps[b * 256 + t];
        double ss = pss[b * 256 + t];
        double L  = pl[b * 256 + t];
        for (int off = 32; off; off >>= 1) {
            s  += __shfl_down(s, off);
            ss += __shfl_down(ss, off);
            L  += __shfl_down(L, off);
        }
        if (lane == 0) { sh_s[w] = s; sh_ss[w] = ss; sh_l[w] = L; }
        __syncthreads();
        if (t == 0) {
            double S  = sh_s[0] + sh_s[1] + sh_s[2] + sh_s[3];
            double SS = sh_ss[0] + sh_ss[1] + sh_ss[2] + sh_ss[3];
            double Lt = sh_l[0] + sh_l[1] + sh_l[2] + sh_l[3];
            double n = (double)HW;
            double var = (SS - S * S / n) / (n - 1.0);
            tot_sh += (double)powf((float)var, 0.2f) * Lt;
        }
        __syncthreads();
    }
    if (t == 0) out[0] = (float)(tot_sh / TOTAL);
}

extern "C" void kernel_launch(void* const* d_in, const int* in_sizes, int n_in,
                              void* d_out, int out_size, void* d_ws, size_t ws_size,
                              hipStream_t stream)
{
    const float* outp = (const float*)d_in[0];
    const float* emap = (const float*)d_in[1];
    const float* gtp  = (const float*)d_in[2];

    char* ws = (char*)d_ws;
    double* ps  = (double*)(ws);
    double* pss = (double*)(ws + 32768);
    double* pl  = (double*)(ws + 65536);

    k_main<<<dim3(16, 16, BB), 256, 0, stream>>>(outp, emap, gtp, ps, pss, pl);
    k_final<<<1, 256, 0, stream>>>(ps, pss, pl, (float*)d_out);
}

// Round 5
// 181.627 us; speedup vs baseline: 1.0586x; 1.0586x over previous
//
#include <hip/hip_runtime.h>
#include <math.h>

#define BB 16
#define CC 3
#define HH 512
#define WW 512
#define HW (HH*WW)            // 262144
#define PLANE4 (HW/4)         // 65536 float4 per channel plane
#define TOTAL ((double)(BB*CC*HW))  // 12582912

// ws layout (bytes):
//   [0)         : float rsr[BB*HW] (sign bit = mask r_sr < r_ema)  16,777,216
//   [16777216)  : double ps[1024]                                       8,192
//   [16785408)  : double pss[1024]                                      8,192
//   [16793600)  : double pl[1024]                                       8,192

// ---------------- K1: streaming residual + encode + variance partials --------
// 1024 blocks x 256 thr x 4 float4 = 4M pixels. 64 blocks per image, each
// covering a contiguous 1/64 slice of the image. Loads fully unrolled and
// independent across the 4 position-groups -> deep MLP (VGPR cap 128).
__global__ __launch_bounds__(256, 4) void k_resid(
    const float4* __restrict__ o4, const float4* __restrict__ e4,
    const float4* __restrict__ g4, float4* __restrict__ rsr4,
    double* __restrict__ ps, double* __restrict__ pss)
{
    const int t   = threadIdx.x;
    const int blk = blockIdx.x;        // 0..1023
    const int img = blk >> 6;          // 64 blocks per image
    const int sub = blk & 63;
    const size_t ib = (size_t)img * (CC * PLANE4);
    const size_t rb = (size_t)img * PLANE4;
    const int p0 = sub * 1024 + t;

    double s_loc = 0.0, ss_loc = 0.0;
#pragma unroll
    for (int pp = 0; pp < 4; ++pp) {
        const int p = p0 + pp * 256;
        float4 rs = {0.f, 0.f, 0.f, 0.f};
        float4 re = {0.f, 0.f, 0.f, 0.f};
#pragma unroll
        for (int c = 0; c < CC; ++c) {
            float4 g = g4[ib + c * PLANE4 + p];
            float4 o = o4[ib + c * PLANE4 + p];
            float4 e = e4[ib + c * PLANE4 + p];
            rs.x += fabsf(g.x - o.x); rs.y += fabsf(g.y - o.y);
            rs.z += fabsf(g.z - o.z); rs.w += fabsf(g.w - o.w);
            re.x += fabsf(g.x - e.x); re.y += fabsf(g.y - e.y);
            re.z += fabsf(g.z - e.z); re.w += fabsf(g.w - e.w);
        }
        float4 enc;
        enc.x = (rs.x < re.x) ? -rs.x : rs.x;
        enc.y = (rs.y < re.y) ? -rs.y : rs.y;
        enc.z = (rs.z < re.z) ? -rs.z : rs.z;
        enc.w = (rs.w < re.w) ? -rs.w : rs.w;
        rsr4[rb + p] = enc;

        s_loc  += (double)rs.x + (double)rs.y + (double)rs.z + (double)rs.w;
        ss_loc += (double)rs.x * rs.x + (double)rs.y * rs.y +
                  (double)rs.z * rs.z + (double)rs.w * rs.w;
    }

    for (int off = 32; off; off >>= 1) {
        s_loc  += __shfl_down(s_loc, off);
        ss_loc += __shfl_down(ss_loc, off);
    }
    __shared__ double red[8];
    const int wid = t >> 6;
    if ((t & 63) == 0) { red[wid] = s_loc; red[4 + wid] = ss_loc; }
    __syncthreads();
    if (t == 0) {
        ps[blk]  = red[0] + red[1] + red[2] + red[3];
        pss[blk] = red[4] + red[5] + red[6] + red[7];
    }
}

// ---------------- K2: full-width 8-row band stencil over rsr -----------------
// Block = rows [r0, r0+8) x 512 of one image; stages rows r0-3..r0+10 plus
// 3-col horizontal reflect halo in LDS. rsr is L3-warm (written by K1).
#define TST 520               // LDS row stride (floats); interior col c -> 4+c
__global__ __launch_bounds__(256, 4) void k_band(
    const float* __restrict__ rsr, double* __restrict__ pl)
{
    __shared__ float tile[14 * TST];
    __shared__ double red[4];
    const int t   = threadIdx.x;
    const int bx  = blockIdx.x;       // 0..63 band
    const int img = blockIdx.y;
    const int r0  = bx * 8;
    const float*  rp  = rsr + (size_t)img * HW;
    const float4* rp4 = (const float4*)rp;

    // stage 14 full rows, float4-coalesced (reflect row map)
#pragma unroll
    for (int it = 0; it < 7; ++it) {
        int idx = it * 256 + t;               // 0..1791
        int lr  = idx >> 7, c4 = idx & 127;
        int gr  = r0 - 3 + lr;
        gr = gr < 0 ? -gr : (gr > HH - 1 ? 2 * HH - 2 - gr : gr);
        *(float4*)&tile[lr * TST + 4 + c4 * 4] = rp4[gr * (WW / 4) + c4];
    }
    // 6 horizontal reflect-halo cols per row (values mirror interior cols)
    if (t < 84) {
        int lr = t / 6, j = t % 6;
        int gr = r0 - 3 + lr;
        gr = gr < 0 ? -gr : (gr > HH - 1 ? 2 * HH - 2 - gr : gr);
        int dst, gx;
        if (j < 3) { dst = 1 + j;        gx = 3 - j;   }   // cols -3..-1 -> 3,2,1
        else       { int jr = j - 3; dst = 516 + jr; gx = 510 - jr; } // 512..514 -> 510,509,508
        tile[lr * TST + dst] = rp[gr * WW + gx];
    }
    __syncthreads();

    // separable 7x7 variance; each thread: 2 cols (t, t+256), 8 output rows,
    // 7-deep register ring of horizontal window sums.
    double accL = 0.0;
#pragma unroll
    for (int cc = 0; cc < 2; ++cc) {
        const int x  = t + cc * 256;          // output col
        const int cb = x + 1;                 // LDS col of window start (4+x-3)
        float rS[7], rSS[7];
        float winS = 0.f, winSS = 0.f;
#pragma unroll
        for (int j = 0; j < 7; ++j) {
            float S = 0.f, SS = 0.f;
#pragma unroll
            for (int dx = 0; dx < 7; ++dx) {
                float v = tile[j * TST + cb + dx];
                S += fabsf(v);
                SS = fmaf(v, v, SS);
            }
            rS[j] = S; rSS[j] = SS;
            winS += S; winSS += SS;
        }
#pragma unroll
        for (int k = 0; k < 8; ++k) {
            if (k) {
                const int slot = k - 1;       // static (unrolled)
                float S = 0.f, SS = 0.f;
#pragma unroll
                for (int dx = 0; dx < 7; ++dx) {
                    float v = tile[(k + 6) * TST + cb + dx];
                    S += fabsf(v);
                    SS = fmaf(v, v, SS);
                }
                winS  += S  - rS[slot];
                winSS += SS - rSS[slot];
                rS[slot] = S; rSS[slot] = SS;
            }
            float cen = tile[(k + 3) * TST + x + 4];
            float rr  = fabsf(cen);
            float pvar = (winSS - winS * winS * (1.0f / 49.0f)) * (1.0f / 48.0f);
            float contrib = (__float_as_uint(cen) >> 31) ? 0.0f : fabsf(pvar) * rr;
            accL += (double)contrib;
        }
    }

    for (int off = 32; off; off >>= 1) accL += __shfl_down(accL, off);
    const int wid = t >> 6;
    if ((t & 63) == 0) red[wid] = accL;
    __syncthreads();
    if (t == 0) pl[img * 64 + bx] = red[0] + red[1] + red[2] + red[3];
}

// ---- final: per-image variance -> patch weight, weighted total, mean --------
__global__ __launch_bounds__(256) void k_final(
    const double* __restrict__ ps, const double* __restrict__ pss,
    const double* __restrict__ pl, float* __restrict__ out)
{
    const int t = threadIdx.x, lane = t & 63, w = t >> 6;
    __shared__ double wacc[4];
    double tot = 0.0;
    for (int m = 0; m < 4; ++m) {
        int b = w * 4 + m;                 // each wave: 4 images
        double s  = ps[b * 64 + lane];
        double ss = pss[b * 64 + lane];
        double L  = pl[b * 64 + lane];
        for (int off = 32; off; off >>= 1) {
            s  += __shfl_down(s, off);
            ss += __shfl_down(ss, off);
            L  += __shfl_down(L, off);
        }
        if (lane == 0) {
            double n = (double)HW;
            double var = (ss - s * s / n) / (n - 1.0);
            tot += (double)powf((float)var, 0.2f) * L;
        }
    }
    if (lane == 0) wacc[w] = tot;
    __syncthreads();
    if (t == 0) out[0] = (float)((wacc[0] + wacc[1] + wacc[2] + wacc[3]) / TOTAL);
}

extern "C" void kernel_launch(void* const* d_in, const int* in_sizes, int n_in,
                              void* d_out, int out_size, void* d_ws, size_t ws_size,
                              hipStream_t stream)
{
    const float4* o4 = (const float4*)d_in[0];
    const float4* e4 = (const float4*)d_in[1];
    const float4* g4 = (const float4*)d_in[2];

    char* ws = (char*)d_ws;
    float4* rsr4 = (float4*)(ws);
    float*  rsr  = (float*)(ws);
    double* ps   = (double*)(ws + 16777216);
    double* pss  = (double*)(ws + 16785408);
    double* pl   = (double*)(ws + 16793600);

    k_resid<<<1024, 256, 0, stream>>>(o4, e4, g4, rsr4, ps, pss);
    k_band<<<dim3(64, BB), 256, 0, stream>>>(rsr, pl);
    k_final<<<1, 256, 0, stream>>>(ps, pss, pl, (float*)d_out);
}

// Round 6
// 177.108 us; speedup vs baseline: 1.0857x; 1.0255x over previous
//
#include <hip/hip_runtime.h>
#include <math.h>

#define BB 16
#define CC 3
#define HH 512
#define WW 512
#define HW (HH*WW)            // 262144
#define PLANE4 (HW/4)         // 65536 float4 per channel plane
#define TOTAL ((double)(BB*CC*HW))  // 12582912

typedef float f32x4 __attribute__((ext_vector_type(4)));

// ws layout (bytes):
//   [0)         : float rsr[BB*HW] (sign bit = mask r_sr < r_ema)  16,777,216
//   [16777216)  : double ps[2048]                                      16,384
//   [16793600)  : double pss[2048]                                     16,384
//   [16809984)  : double pl[1024]                                       8,192

// ---------------- K1: streaming residual, forced 18-deep MLP -----------------
// 2048 blocks x 256 thr x 2 float4. All 18 loads issued back-to-back; a single
// asm keep-alive pins all destinations live -> 18 global_load_dwordx4 in
// flight per thread before the first consume.
__global__ __launch_bounds__(256, 4) void k_resid(
    const f32x4* __restrict__ o4, const f32x4* __restrict__ e4,
    const f32x4* __restrict__ g4, f32x4* __restrict__ rsr4,
    double* __restrict__ ps, double* __restrict__ pss)
{
    const int t   = threadIdx.x;
    const int blk = blockIdx.x;        // 0..2047
    const int img = blk >> 7;          // 128 blocks per image
    const int sub = blk & 127;
    const size_t ib = (size_t)img * (CC * PLANE4);
    const size_t rb = (size_t)img * PLANE4;
    const int pA = sub * 512 + t;
    const int pB = pA + 256;

    f32x4 gA0 = g4[ib + 0 * PLANE4 + pA];
    f32x4 gA1 = g4[ib + 1 * PLANE4 + pA];
    f32x4 gA2 = g4[ib + 2 * PLANE4 + pA];
    f32x4 oA0 = o4[ib + 0 * PLANE4 + pA];
    f32x4 oA1 = o4[ib + 1 * PLANE4 + pA];
    f32x4 oA2 = o4[ib + 2 * PLANE4 + pA];
    f32x4 eA0 = e4[ib + 0 * PLANE4 + pA];
    f32x4 eA1 = e4[ib + 1 * PLANE4 + pA];
    f32x4 eA2 = e4[ib + 2 * PLANE4 + pA];
    f32x4 gB0 = g4[ib + 0 * PLANE4 + pB];
    f32x4 gB1 = g4[ib + 1 * PLANE4 + pB];
    f32x4 gB2 = g4[ib + 2 * PLANE4 + pB];
    f32x4 oB0 = o4[ib + 0 * PLANE4 + pB];
    f32x4 oB1 = o4[ib + 1 * PLANE4 + pB];
    f32x4 oB2 = o4[ib + 2 * PLANE4 + pB];
    f32x4 eB0 = e4[ib + 0 * PLANE4 + pB];
    f32x4 eB1 = e4[ib + 1 * PLANE4 + pB];
    f32x4 eB2 = e4[ib + 2 * PLANE4 + pB];

    // Pin all 18 load destinations live at one point -> loads issue clustered.
    asm volatile("" ::
        "v"(gA0), "v"(gA1), "v"(gA2), "v"(oA0), "v"(oA1), "v"(oA2),
        "v"(eA0), "v"(eA1), "v"(eA2),
        "v"(gB0), "v"(gB1), "v"(gB2), "v"(oB0), "v"(oB1), "v"(oB2),
        "v"(eB0), "v"(eB1), "v"(eB2));

    double s_loc = 0.0, ss_loc = 0.0;
    f32x4 encA, encB;
#pragma unroll
    for (int j = 0; j < 4; ++j) {
        float rs = fabsf(gA0[j] - oA0[j]) + fabsf(gA1[j] - oA1[j]) + fabsf(gA2[j] - oA2[j]);
        float re = fabsf(gA0[j] - eA0[j]) + fabsf(gA1[j] - eA1[j]) + fabsf(gA2[j] - eA2[j]);
        encA[j] = (rs < re) ? -rs : rs;
        s_loc += (double)rs;
        ss_loc += (double)rs * rs;
    }
#pragma unroll
    for (int j = 0; j < 4; ++j) {
        float rs = fabsf(gB0[j] - oB0[j]) + fabsf(gB1[j] - oB1[j]) + fabsf(gB2[j] - oB2[j]);
        float re = fabsf(gB0[j] - eB0[j]) + fabsf(gB1[j] - eB1[j]) + fabsf(gB2[j] - eB2[j]);
        encB[j] = (rs < re) ? -rs : rs;
        s_loc += (double)rs;
        ss_loc += (double)rs * rs;
    }
    rsr4[rb + pA] = encA;
    rsr4[rb + pB] = encB;

    for (int off = 32; off; off >>= 1) {
        s_loc  += __shfl_down(s_loc, off);
        ss_loc += __shfl_down(ss_loc, off);
    }
    __shared__ double red[8];
    const int wid = t >> 6;
    if ((t & 63) == 0) { red[wid] = s_loc; red[4 + wid] = ss_loc; }
    __syncthreads();
    if (t == 0) {
        ps[blk]  = red[0] + red[1] + red[2] + red[3];
        pss[blk] = red[4] + red[5] + red[6] + red[7];
    }
}

// ---------------- K2: full-width 8-row band stencil over rsr -----------------
#define TST 520               // LDS row stride (floats); interior col c -> 4+c
__global__ __launch_bounds__(256, 4) void k_band(
    const float* __restrict__ rsr, double* __restrict__ pl)
{
    __shared__ float tile[14 * TST];
    __shared__ double red[4];
    const int t   = threadIdx.x;
    const int bx  = blockIdx.x;       // 0..63 band
    const int img = blockIdx.y;
    const int r0  = bx * 8;
    const float*  rp  = rsr + (size_t)img * HW;
    const float4* rp4 = (const float4*)rp;

    // stage 14 full rows, float4-coalesced (reflect row map)
#pragma unroll
    for (int it = 0; it < 7; ++it) {
        int idx = it * 256 + t;               // 0..1791
        int lr  = idx >> 7, c4 = idx & 127;
        int gr  = r0 - 3 + lr;
        gr = gr < 0 ? -gr : (gr > HH - 1 ? 2 * HH - 2 - gr : gr);
        *(float4*)&tile[lr * TST + 4 + c4 * 4] = rp4[gr * (WW / 4) + c4];
    }
    // 6 horizontal reflect-halo cols per row
    if (t < 84) {
        int lr = t / 6, j = t % 6;
        int gr = r0 - 3 + lr;
        gr = gr < 0 ? -gr : (gr > HH - 1 ? 2 * HH - 2 - gr : gr);
        int dst, gx;
        if (j < 3) { dst = 1 + j;        gx = 3 - j;   }
        else       { int jr = j - 3; dst = 516 + jr; gx = 510 - jr; }
        tile[lr * TST + dst] = rp[gr * WW + gx];
    }
    __syncthreads();

    double accL = 0.0;
#pragma unroll
    for (int cc = 0; cc < 2; ++cc) {
        const int x  = t + cc * 256;          // output col
        const int cb = x + 1;                 // LDS col of window start
        float rS[7], rSS[7];
        float winS = 0.f, winSS = 0.f;
#pragma unroll
        for (int j = 0; j < 7; ++j) {
            float S = 0.f, SS = 0.f;
#pragma unroll
            for (int dx = 0; dx < 7; ++dx) {
                float v = tile[j * TST + cb + dx];
                S += fabsf(v);
                SS = fmaf(v, v, SS);
            }
            rS[j] = S; rSS[j] = SS;
            winS += S; winSS += SS;
        }
#pragma unroll
        for (int k = 0; k < 8; ++k) {
            if (k) {
                const int slot = k - 1;
                float S = 0.f, SS = 0.f;
#pragma unroll
                for (int dx = 0; dx < 7; ++dx) {
                    float v = tile[(k + 6) * TST + cb + dx];
                    S += fabsf(v);
                    SS = fmaf(v, v, SS);
                }
                winS  += S  - rS[slot];
                winSS += SS - rSS[slot];
                rS[slot] = S; rSS[slot] = SS;
            }
            float cen = tile[(k + 3) * TST + x + 4];
            float rr  = fabsf(cen);
            float pvar = (winSS - winS * winS * (1.0f / 49.0f)) * (1.0f / 48.0f);
            float contrib = (__float_as_uint(cen) >> 31) ? 0.0f : fabsf(pvar) * rr;
            accL += (double)contrib;
        }
    }

    for (int off = 32; off; off >>= 1) accL += __shfl_down(accL, off);
    const int wid = t >> 6;
    if ((t & 63) == 0) red[wid] = accL;
    __syncthreads();
    if (t == 0) pl[img * 64 + bx] = red[0] + red[1] + red[2] + red[3];
}

// ---- final: per-image variance -> patch weight, weighted total, mean --------
__global__ __launch_bounds__(256) void k_final(
    const double* __restrict__ ps, const double* __restrict__ pss,
    const double* __restrict__ pl, float* __restrict__ out)
{
    const int t = threadIdx.x, lane = t & 63, w = t >> 6;
    __shared__ double wacc[4];
    double tot = 0.0;
    for (int m = 0; m < 4; ++m) {
        int b = w * 4 + m;                 // each wave: 4 images
        double s  = ps[b * 128 + lane] + ps[b * 128 + 64 + lane];
        double ss = pss[b * 128 + lane] + pss[b * 128 + 64 + lane];
        double L  = pl[b * 64 + lane];
        for (int off = 32; off; off >>= 1) {
            s  += __shfl_down(s, off);
            ss += __shfl_down(ss, off);
            L  += __shfl_down(L, off);
        }
        if (lane == 0) {
            double n = (double)HW;
            double var = (ss - s * s / n) / (n - 1.0);
            tot += (double)powf((float)var, 0.2f) * L;
        }
    }
    if (lane == 0) wacc[w] = tot;
    __syncthreads();
    if (t == 0) out[0] = (float)((wacc[0] + wacc[1] + wacc[2] + wacc[3]) / TOTAL);
}

extern "C" void kernel_launch(void* const* d_in, const int* in_sizes, int n_in,
                              void* d_out, int out_size, void* d_ws, size_t ws_size,
                              hipStream_t stream)
{
    const f32x4* o4 = (const f32x4*)d_in[0];
    const f32x4* e4 = (const f32x4*)d_in[1];
    const f32x4* g4 = (const f32x4*)d_in[2];

    char* ws = (char*)d_ws;
    f32x4*  rsr4 = (f32x4*)(ws);
    float*  rsr  = (float*)(ws);
    double* ps   = (double*)(ws + 16777216);
    double* pss  = (double*)(ws + 16793600);
    double* pl   = (double*)(ws + 16809984);

    k_resid<<<2048, 256, 0, stream>>>(o4, e4, g4, rsr4, ps, pss);
    k_band<<<dim3(64, BB), 256, 0, stream>>>(rsr, pl);
    k_final<<<1, 256, 0, stream>>>(ps, pss, pl, (float*)d_out);
}

// Round 8
// 169.141 us; speedup vs baseline: 1.1368x; 1.0471x over previous
//
#include <hip/hip_runtime.h>
#include <math.h>

#define BB 16
#define CC 3
#define HH 512
#define WW 512
#define HW (HH*WW)            // 262144
#define PLANE4 (HW/4)         // 65536 float4 per channel plane
#define W4 (WW/4)             // 128 float4 per row
#define TOTAL ((double)(BB*CC*HW))  // 12582912

typedef float f32x4 __attribute__((ext_vector_type(4)));

#define TSTR 72               // LDS tile row stride in floats (col = rel+4, rel in [-4,68))

// ws layout (bytes):
//   [0)     : double ps[2048]   per-block interior sum of r_sr
//   [16384) : double pss[2048]  per-block interior sum of r_sr^2
//   [32768) : double pl[2048]   per-block loss partial (no patch weight)

// One block = 32-row x 64-col output tile (grid 8 x 16 x 16 = 2048 blocks).
// LDS holds encoded r_sr for the 38 x 72 staged region (halo 3 + f4 padding).
__global__ __launch_bounds__(256, 4) void k_main(
    const f32x4* __restrict__ o4, const f32x4* __restrict__ e4,
    const f32x4* __restrict__ g4,
    double* __restrict__ ps, double* __restrict__ pss, double* __restrict__ pl)
{
    __shared__ float tile[38 * TSTR];
    __shared__ double red[12];

    const int t  = threadIdx.x;
    const int bx = blockIdx.x;        // 0..7   (64-col tiles)
    const int by = blockIdx.y;        // 0..15  (32-row tiles)
    const int b  = blockIdx.z;        // image
    const int y0 = by * 32;
    const size_t ib = (size_t)b * (CC * PLANE4);

    double s_loc = 0.0, ss_loc = 0.0;

    // ---- Phase A: stage 38 rows x 18 float4 (684 tasks), compute r inline ----
    for (int i = t; i < 38 * 18; i += 256) {
        const int lr = i / 18;
        const int lc = i - lr * 18;
        int gy = y0 - 3 + lr;
        gy = gy < 0 ? -gy : (gy > HH - 1 ? 2 * HH - 2 - gy : gy);
        const int gx4 = bx * 16 - 1 + lc;
        const bool interior = (lr >= 3) & (lr < 35) & (lc >= 1) & (lc < 17);

        if (gx4 >= 0 && gx4 < W4) {
            const size_t idx = ib + (size_t)gy * W4 + gx4;
            f32x4 g0 = g4[idx];
            f32x4 g1 = g4[idx + PLANE4];
            f32x4 g2 = g4[idx + 2 * PLANE4];
            f32x4 q0 = o4[idx];
            f32x4 q1 = o4[idx + PLANE4];
            f32x4 q2 = o4[idx + 2 * PLANE4];
            f32x4 rsv;
#pragma unroll
            for (int j = 0; j < 4; ++j)
                rsv[j] = fabsf(g0[j] - q0[j]) + fabsf(g1[j] - q1[j]) + fabsf(g2[j] - q2[j]);

            if (interior) {
                f32x4 e0 = e4[idx];
                f32x4 e1 = e4[idx + PLANE4];
                f32x4 e2 = e4[idx + 2 * PLANE4];
                f32x4 enc;
#pragma unroll
                for (int j = 0; j < 4; ++j) {
                    float re = fabsf(g0[j] - e0[j]) + fabsf(g1[j] - e1[j]) + fabsf(g2[j] - e2[j]);
                    float rs = rsv[j];
                    enc[j] = (rs < re) ? -rs : rs;
                    s_loc  += (double)rs;
                    ss_loc += (double)rs * rs;
                }
                *(f32x4*)&tile[lr * TSTR + lc * 4] = enc;
            } else {
                *(f32x4*)&tile[lr * TSTR + lc * 4] = rsv;   // halo: sign clear
            }
        } else {
            // out-of-range f4 column (only bx==0 lc==0, or bx==7 lc==17): scalar reflect
            const float* gp = (const float*)g4;
            const float* op = (const float*)o4;
#pragma unroll
            for (int j = 0; j < 4; ++j) {
                int gx = gx4 * 4 + j;
                gx = gx < 0 ? -gx : (gx > WW - 1 ? 2 * WW - 2 - gx : gx);
                const size_t idx = ib * 4 + (size_t)gy * WW + gx;
                float r = 0.f;
#pragma unroll
                for (int c = 0; c < CC; ++c)
                    r += fabsf(gp[idx + c * HW] - op[idx + c * HW]);
                tile[lr * TSTR + lc * 4 + j] = r;
            }
        }
    }
    __syncthreads();

    // ---- Phase B: separable 7x7 variance, 7-deep register ring --------------
    const int x  = t & 63;            // output col 0..63
    const int w  = t >> 6;            // strip of 8 output rows
    const int r0 = w * 8;

    float rS[7], rSS[7];
    float winS = 0.f, winSS = 0.f;
#pragma unroll
    for (int j = 0; j < 7; ++j) {
        float S = 0.f, SS = 0.f;
#pragma unroll
        for (int dx = 0; dx < 7; ++dx) {
            float v = tile[(r0 + j) * TSTR + x + 1 + dx];
            S += fabsf(v);
            SS = fmaf(v, v, SS);
        }
        rS[j] = S; rSS[j] = SS;
        winS += S; winSS += SS;
    }
    double acc = 0.0;
#pragma unroll
    for (int k = 0; k < 8; ++k) {
        if (k) {
            const int slot = k - 1;            // static (unrolled)
            float S = 0.f, SS = 0.f;
#pragma unroll
            for (int dx = 0; dx < 7; ++dx) {
                float v = tile[(r0 + k + 6) * TSTR + x + 1 + dx];
                S += fabsf(v);
                SS = fmaf(v, v, SS);
            }
            winS  += S  - rS[slot];
            winSS += SS - rSS[slot];
            rS[slot] = S; rSS[slot] = SS;
        }
        float cen = tile[(r0 + k + 3) * TSTR + x + 4];
        float rr  = fabsf(cen);
        float pvar = (winSS - winS * winS * (1.0f / 49.0f)) * (1.0f / 48.0f);
        float contrib = (__float_as_uint(cen) >> 31) ? 0.0f : fabsf(pvar) * rr;
        acc += (double)contrib;
    }

    // ---- block reduction -> per-block slots ---------------------------------
    for (int off = 32; off; off >>= 1) {
        s_loc  += __shfl_down(s_loc, off);
        ss_loc += __shfl_down(ss_loc, off);
        acc    += __shfl_down(acc, off);
    }
    const int wid = t >> 6;
    if ((t & 63) == 0) { red[wid] = s_loc; red[4 + wid] = ss_loc; red[8 + wid] = acc; }
    __syncthreads();
    if (t == 0) {
        const int bid = (b * 16 + by) * 8 + bx;     // 0..2047
        ps[bid]  = red[0] + red[1] + red[2] + red[3];
        pss[bid] = red[4] + red[5] + red[6] + red[7];
        pl[bid]  = red[8] + red[9] + red[10] + red[11];
    }
}

// ---- final: per-image variance -> patch weight, weighted total, mean --------
__global__ __launch_bounds__(256) void k_final(
    const double* __restrict__ ps, const double* __restrict__ pss,
    const double* __restrict__ pl, float* __restrict__ out)
{
    const int t = threadIdx.x, lane = t & 63, w = t >> 6;
    __shared__ double wacc[4];
    double tot = 0.0;
    for (int m = 0; m < 4; ++m) {
        int b = w * 4 + m;                 // each wave: 4 images, 128 partials each
        double s  = ps[b * 128 + lane] + ps[b * 128 + 64 + lane];
        double ss = pss[b * 128 + lane] + pss[b * 128 + 64 + lane];
        double L  = pl[b * 128 + lane] + pl[b * 128 + 64 + lane];
        for (int off = 32; off; off >>= 1) {
            s  += __shfl_down(s, off);
            ss += __shfl_down(ss, off);
            L  += __shfl_down(L, off);
        }
        if (lane == 0) {
            double n = (double)HW;
            double var = (ss - s * s / n) / (n - 1.0);
            tot += (double)powf((float)var, 0.2f) * L;
        }
    }
    if (lane == 0) wacc[w] = tot;
    __syncthreads();
    if (t == 0) out[0] = (float)((wacc[0] + wacc[1] + wacc[2] + wacc[3]) / TOTAL);
}

extern "C" void kernel_launch(void* const* d_in, const int* in_sizes, int n_in,
                              void* d_out, int out_size, void* d_ws, size_t ws_size,
                              hipStream_t stream)
{
    const f32x4* o4 = (const f32x4*)d_in[0];
    const f32x4* e4 = (const f32x4*)d_in[1];
    const f32x4* g4 = (const f32x4*)d_in[2];

    char* ws = (char*)d_ws;
    double* ps  = (double*)(ws);
    double* pss = (double*)(ws + 16384);
    double* pl  = (double*)(ws + 32768);

    k_main<<<dim3(8, 16, BB), 256, 0, stream>>>(o4, e4, g4, ps, pss, pl);
    k_final<<<1, 256, 0, stream>>>(ps, pss, pl, (float*)d_out);
}